// Round 4
// baseline (632.457 us; speedup 1.0000x reference)
//
#include <hip/hip_runtime.h>
#include <hip/hip_bf16.h>

// B=4, S=1024, E=1024, H=16, D=64, F=4096. N=B*S=4096 tokens.
// GEMMs + attention core: bf16 MFMA (fp32 accumulate). LN/softmax: fp32.

typedef __attribute__((ext_vector_type(8))) short s16x8;
typedef __attribute__((ext_vector_type(4))) float f32x4;

static __device__ __forceinline__ unsigned short f2bf(float x) {
  unsigned int u = __builtin_bit_cast(unsigned int, x);
  u = (u + 0x7fffu + ((u >> 16) & 1u)) >> 16;  // RNE
  return (unsigned short)u;
}

// ---------------------------------------------------------------------------
// fp32 -> bf16 weight conversion
// ---------------------------------------------------------------------------
__global__ __launch_bounds__(256) void cvt_bf16(const float* __restrict__ src,
                                                unsigned short* __restrict__ dst,
                                                int n) {
  const int i = (blockIdx.x * 256 + threadIdx.x) * 4;
  if (i < n) {
    const float4 v = *(const float4*)(src + i);
    ushort4 o;
    o.x = f2bf(v.x); o.y = f2bf(v.y); o.z = f2bf(v.z); o.w = f2bf(v.w);
    *(ushort4*)(dst + i) = o;
  }
}

// ---------------------------------------------------------------------------
// LayerNorm over E=1024, one block per row, bf16 output.
// ---------------------------------------------------------------------------
__global__ __launch_bounds__(256) void ln_kernel(const float* __restrict__ x,
                                                 const float* __restrict__ g,
                                                 const float* __restrict__ bvec,
                                                 unsigned short* __restrict__ y) {
  const int row = blockIdx.x;
  const int t = threadIdx.x;
  const float4 v = ((const float4*)(x + (size_t)row * 1024))[t];
  float s = v.x + v.y + v.z + v.w;
  float ss = v.x * v.x + v.y * v.y + v.z * v.z + v.w * v.w;
#pragma unroll
  for (int off = 32; off > 0; off >>= 1) {
    s += __shfl_down(s, off);
    ss += __shfl_down(ss, off);
  }
  __shared__ float sb[4], ssb[4];
  __shared__ float mrs[2];
  if ((t & 63) == 0) { sb[t >> 6] = s; ssb[t >> 6] = ss; }
  __syncthreads();
  if (t == 0) {
    float ts = sb[0] + sb[1] + sb[2] + sb[3];
    float tss = ssb[0] + ssb[1] + ssb[2] + ssb[3];
    float mean = ts * (1.0f / 1024.0f);
    float var = tss * (1.0f / 1024.0f) - mean * mean;
    mrs[0] = mean;
    mrs[1] = rsqrtf(var + 1e-5f);
  }
  __syncthreads();
  const float mean = mrs[0], rstd = mrs[1];
  const float4 gg = ((const float4*)g)[t];
  const float4 bb = ((const float4*)bvec)[t];
  ushort4 o;
  o.x = f2bf((v.x - mean) * rstd * gg.x + bb.x);
  o.y = f2bf((v.y - mean) * rstd * gg.y + bb.y);
  o.z = f2bf((v.z - mean) * rstd * gg.z + bb.z);
  o.w = f2bf((v.w - mean) * rstd * gg.w + bb.w);
  *(ushort4*)(y + (size_t)row * 1024 + t * 4) = o;
}

// ---------------------------------------------------------------------------
// C[M,N] = A[M,K] @ W[N,K]^T + bias   -- bf16 MFMA, fp32 accum.
// 128x128 tile, BK=32, 256 threads = 4 waves (2x2), 4x4 frags of 16x16x32.
// EPI: 1 = fp32 +res store, 2 = exact GELU -> bf16, 3 = QKV split:
//      cols<2048 -> bf16 qkv2[row][2048]; cols>=2048 -> bf16 vt (V transposed)
// ---------------------------------------------------------------------------
template <int EPI>
__global__ __launch_bounds__(256) void gemm_bf16(
    const unsigned short* __restrict__ A, const unsigned short* __restrict__ W,
    const float* __restrict__ bias, const float* __restrict__ res, void* Cv,
    void* aux, int M, int N, int K) {
  __shared__ unsigned short As[128][40];  // pitch 40 (80B): 2-way alias (free)
  __shared__ unsigned short Bs[128][40];
  const int t = threadIdx.x;
  const int m0 = blockIdx.y << 7;
  const int n0 = blockIdx.x << 7;
  const int srow = t >> 2, sch = t & 3;
  const unsigned short* Ap0 = A + (size_t)(m0 + srow) * K + sch * 8;
  const unsigned short* Ap1 = A + (size_t)(m0 + srow + 64) * K + sch * 8;
  const unsigned short* Bp0 = W + (size_t)(n0 + srow) * K + sch * 8;
  const unsigned short* Bp1 = W + (size_t)(n0 + srow + 64) * K + sch * 8;
  const int l = t & 63;
  const int w = t >> 6;
  const int wr = (w >> 1) * 64, wc = (w & 1) * 64;
  const int lr = l & 15;
  const int kc = (l >> 4) * 8;
  f32x4 acc[4][4] = {};
  for (int k0 = 0; k0 < K; k0 += 32) {
    const uint4 a0 = *(const uint4*)(Ap0 + k0);
    const uint4 a1 = *(const uint4*)(Ap1 + k0);
    const uint4 b0 = *(const uint4*)(Bp0 + k0);
    const uint4 b1 = *(const uint4*)(Bp1 + k0);
    __syncthreads();
    *(uint4*)&As[srow][sch * 8] = a0;
    *(uint4*)&As[srow + 64][sch * 8] = a1;
    *(uint4*)&Bs[srow][sch * 8] = b0;
    *(uint4*)&Bs[srow + 64][sch * 8] = b1;
    __syncthreads();
    s16x8 af[4], bfr[4];
#pragma unroll
    for (int i = 0; i < 4; ++i) af[i] = *(const s16x8*)&As[wr + i * 16 + lr][kc];
#pragma unroll
    for (int j = 0; j < 4; ++j) bfr[j] = *(const s16x8*)&Bs[wc + j * 16 + lr][kc];
#pragma unroll
    for (int i = 0; i < 4; ++i)
#pragma unroll
      for (int j = 0; j < 4; ++j)
        acc[i][j] = __builtin_amdgcn_mfma_f32_16x16x32_bf16(af[i], bfr[j],
                                                            acc[i][j], 0, 0, 0);
  }
  // C/D layout: col = lane&15, row = (lane>>4)*4 + reg   [HW-verified]
  const int lg4 = (l >> 4) * 4;
#pragma unroll
  for (int j = 0; j < 4; ++j) {
    const int col = n0 + wc + j * 16 + lr;
    const float bj = bias[col];
#pragma unroll
    for (int i = 0; i < 4; ++i) {
      const int row0 = m0 + wr + i * 16 + lg4;
#pragma unroll
      for (int r = 0; r < 4; ++r) {
        const int row = row0 + r;
        const size_t idx = (size_t)row * N + col;
        float o = acc[i][j][r] + bj;
        if (EPI == 1) {
          ((float*)Cv)[idx] = o + res[idx];
        } else if (EPI == 2) {
          o = 0.5f * o * (1.0f + erff(o * 0.70710678118654752f));
          ((unsigned short*)Cv)[idx] = f2bf(o);
        } else {  // EPI == 3: QKV split (each n-tile is uniformly Q/K or V)
          if (col < 2048) {
            ((unsigned short*)Cv)[(size_t)row * 2048 + col] = f2bf(o);
          } else {
            // vt[b*1024 + dv][s] ; b = row>>10, s = row&1023, dv = col-2048
            const size_t vidx =
                ((size_t)((row >> 10) << 10) + (col - 2048)) * 1024 +
                (row & 1023);
            ((unsigned short*)aux)[vidx] = f2bf(o);
          }
        }
      }
    }
  }
}

// ---------------------------------------------------------------------------
// MFMA attention. Grid 256 = (b, 16-row q-tile), 512 threads = 8 waves.
// qkv2: bf16 [token][2048] (Q at 0, K at 1024). vt: bf16 [b*16+h][64 d][1024 s].
// Per head: QK^T (waves split keys 8-way) -> fp32 Sc -> wave-parallel softmax
// -> head-mean RMW into attnw + PV MFMA (j=w&3, khalf=w>>2) -> 2-way reduce
// -> bf16 ctx. Fragment patterns identical to the verified GEMM mapping.
// ---------------------------------------------------------------------------
__global__ __launch_bounds__(512, 4) void attn_mfma(
    const unsigned short* __restrict__ qkv2,
    const unsigned short* __restrict__ vt, unsigned short* __restrict__ ctx,
    float* __restrict__ attnw) {
  constexpr int PITCH = 1044;  // dwords
  __shared__ float Sc[16][PITCH];   // 66816 B
  __shared__ float Pctx[2][1024];   // 8 KB partial ctx [khalf][q*64+d]
  __shared__ float invs[16];
  const int t = threadIdx.x;
  const int w = t >> 6, l = t & 63;
  const int lr = l & 15, lg = l >> 4;
  const int b = blockIdx.x >> 6;
  const int q0 = (blockIdx.x & 63) * 16;
  const size_t qkbase = (size_t)b * 1024 * 2048;
  const unsigned short* Qrow = qkv2 + qkbase + (size_t)(q0 + lr) * 2048;
  const int j = w & 3, kh = w >> 2;

#pragma unroll 1
  for (int h = 0; h < 16; ++h) {
    const int hoff = h * 64;
    // ---- Q A-frags (d-chunks 0-31, 32-63) ----
    s16x8 qf0 = *(const s16x8*)(Qrow + hoff + lg * 8);
    s16x8 qf1 = *(const s16x8*)(Qrow + hoff + 32 + lg * 8);
    // ---- QK^T: wave w handles keys [w*128, w*128+128), 8 tiles of 16 ----
    const unsigned short* Kb = qkv2 + qkbase + 1024 + hoff + lg * 8;
#pragma unroll
    for (int kt = 0; kt < 8; ++kt) {
      const int key0 = w * 128 + kt * 16;
      const unsigned short* kp = Kb + (size_t)(key0 + lr) * 2048;
      const s16x8 kf0 = *(const s16x8*)kp;
      const s16x8 kf1 = *(const s16x8*)(kp + 32);
      f32x4 s = {0.f, 0.f, 0.f, 0.f};
      s = __builtin_amdgcn_mfma_f32_16x16x32_bf16(qf0, kf0, s, 0, 0, 0);
      s = __builtin_amdgcn_mfma_f32_16x16x32_bf16(qf1, kf1, s, 0, 0, 0);
#pragma unroll
      for (int r = 0; r < 4; ++r)
        Sc[lg * 4 + r][key0 + lr] = s[r] * 0.125f;
    }
    __syncthreads();
    // ---- softmax: 32 threads per row, float4 passes ----
    {
      const int r = t >> 5, c0 = t & 31;
      float m = -3.4e38f;
#pragma unroll
      for (int i = 0; i < 8; ++i) {
        const float4 f = *(const float4*)&Sc[r][(c0 + 32 * i) * 4];
        m = fmaxf(m, fmaxf(fmaxf(f.x, f.y), fmaxf(f.z, f.w)));
      }
#pragma unroll
      for (int off = 1; off < 32; off <<= 1) m = fmaxf(m, __shfl_xor(m, off));
      float sum = 0.f;
#pragma unroll
      for (int i = 0; i < 8; ++i) {
        float4* p = (float4*)&Sc[r][(c0 + 32 * i) * 4];
        float4 f = *p;
        f.x = __expf(f.x - m); f.y = __expf(f.y - m);
        f.z = __expf(f.z - m); f.w = __expf(f.w - m);
        sum += f.x + f.y + f.z + f.w;
        *p = f;
      }
#pragma unroll
      for (int off = 1; off < 32; off <<= 1) sum += __shfl_xor(sum, off);
      if (c0 == 0) invs[r] = 1.0f / sum;
    }
    __syncthreads();
    // ---- head-mean RMW into attnw (block owns slice; h==0 overwrites) ----
    {
      const int r = t >> 5, c0 = t & 31;
      const float sc = invs[r] * 0.0625f;
      float4* dst = (float4*)(attnw + (size_t)(b * 1024 + q0 + r) * 1024);
#pragma unroll
      for (int i = 0; i < 8; ++i) {
        const int f = c0 + 32 * i;
        const float4 p = *(const float4*)&Sc[r][f * 4];
        float4 val = make_float4(p.x * sc, p.y * sc, p.z * sc, p.w * sc);
        if (h == 0) {
          dst[f] = val;
        } else {
          const float4 o = dst[f];
          dst[f] = make_float4(o.x + val.x, o.y + val.y, o.z + val.z,
                               o.w + val.w);
        }
      }
    }
    // ---- PV: partial ctx over khalf, 16 MFMA groups of 32 keys ----
    {
      const unsigned short* Vb =
          vt + ((size_t)(b * 16 + h) * 64 + j * 16 + lr) * 1024 + lg * 8;
      f32x4 acc = {0.f, 0.f, 0.f, 0.f};
#pragma unroll
      for (int g = 0; g < 16; ++g) {
        const int k0 = kh * 512 + g * 32;
        const f32x4 p0 = *(const f32x4*)&Sc[lr][k0 + lg * 8];
        const f32x4 p1 = *(const f32x4*)&Sc[lr][k0 + lg * 8 + 4];
        s16x8 pa;
#pragma unroll
        for (int i = 0; i < 4; ++i) {
          pa[i] = (short)f2bf(p0[i]);
          pa[4 + i] = (short)f2bf(p1[i]);
        }
        const s16x8 vb = *(const s16x8*)(Vb + k0);
        acc = __builtin_amdgcn_mfma_f32_16x16x32_bf16(pa, vb, acc, 0, 0, 0);
      }
#pragma unroll
      for (int r = 0; r < 4; ++r)
        Pctx[kh][(lg * 4 + r) * 64 + j * 16 + lr] = acc[r];
    }
    __syncthreads();
    // ---- 2-way reduce + normalized bf16 ctx store ----
    for (int e = t; e < 1024; e += 512) {
      const int q = e >> 6, d = e & 63;
      const float v = (Pctx[0][e] + Pctx[1][e]) * invs[q];
      ctx[(size_t)(b * 1024 + q0 + q) * 1024 + hoff + d] = f2bf(v);
    }
    // head-boundary hazards: next head's Sc writes only follow this head's
    // pre-barrier Sc reads; Pctx/invs protected by next head's two barriers.
  }
}

// ---------------------------------------------------------------------------
extern "C" void kernel_launch(void* const* d_in, const int* in_sizes, int n_in,
                              void* d_out, int out_size, void* d_ws,
                              size_t ws_size, hipStream_t stream) {
  const float* query = (const float*)d_in[0];
  const float* ln1_g = (const float*)d_in[1];
  const float* ln1_b = (const float*)d_in[2];
  const float* in_w = (const float*)d_in[3];
  const float* in_b = (const float*)d_in[4];
  const float* out_w = (const float*)d_in[5];
  const float* out_b = (const float*)d_in[6];
  const float* ln2_g = (const float*)d_in[7];
  const float* ln2_b = (const float*)d_in[8];
  const float* w1 = (const float*)d_in[9];
  const float* b1 = (const float*)d_in[10];
  const float* w2 = (const float*)d_in[11];
  const float* b2 = (const float*)d_in[12];
  float* out = (float*)d_out;

  char* wsb = (char*)d_ws;
  const size_t MB = 1u << 20;
  unsigned short* wbf_in = (unsigned short*)(wsb);             // 6 MB
  unsigned short* wbf_out = (unsigned short*)(wsb + 6 * MB);   // 2 MB
  unsigned short* wbf_w1 = (unsigned short*)(wsb + 8 * MB);    // 8 MB
  unsigned short* wbf_w2 = (unsigned short*)(wsb + 16 * MB);   // 8 MB
  unsigned short* nq_bf = (unsigned short*)(wsb + 24 * MB);    // 8 MB
  unsigned short* qkv2 = (unsigned short*)(wsb + 32 * MB);     // 16 MB (Q,K)
  unsigned short* vt = (unsigned short*)(wsb + 48 * MB);       // 8 MB (V^T)
  unsigned short* ctx_bf = (unsigned short*)(wsb + 56 * MB);   // 8 MB
  unsigned short* mlph_bf = (unsigned short*)(wsb + 32 * MB);  // 32 MB (reuse)

  float* x1 = out;                                   // [B,S,E]
  float* attnw = out + (size_t)4 * 1024 * 1024;      // [B,S,S]

  constexpr int NROW = 4096;

  // 0) weights -> bf16
  cvt_bf16<<<3072, 256, 0, stream>>>(in_w, wbf_in, 3 * 1024 * 1024);
  cvt_bf16<<<1024, 256, 0, stream>>>(out_w, wbf_out, 1024 * 1024);
  cvt_bf16<<<4096, 256, 0, stream>>>(w1, wbf_w1, 4 * 1024 * 1024);
  cvt_bf16<<<4096, 256, 0, stream>>>(w2, wbf_w2, 4 * 1024 * 1024);
  // 1) LN1 -> bf16
  ln_kernel<<<NROW, 256, 0, stream>>>(query, ln1_g, ln1_b, nq_bf);
  // 2) QKV projection -> bf16 Q,K packed + V transposed
  gemm_bf16<3><<<dim3(24, 32), 256, 0, stream>>>(nq_bf, wbf_in, in_b, nullptr,
                                                 qkv2, vt, NROW, 3072, 1024);
  // 3) MFMA attention (bf16 ctx + fp32 head-mean attn weights)
  attn_mfma<<<256, 512, 0, stream>>>(qkv2, vt, ctx_bf, attnw);
  // 4) out_proj + residual(query) -> x1 (fp32, in d_out)
  gemm_bf16<1><<<dim3(8, 32), 256, 0, stream>>>(ctx_bf, wbf_out, out_b, query,
                                                x1, nullptr, NROW, 1024, 1024);
  // 5) LN2 -> bf16
  ln_kernel<<<NROW, 256, 0, stream>>>(x1, ln2_g, ln2_b, nq_bf);
  // 6) MLP fc1 + exact GELU -> bf16
  gemm_bf16<2><<<dim3(32, 32), 256, 0, stream>>>(nq_bf, wbf_w1, b1, nullptr,
                                                 mlph_bf, nullptr, NROW, 4096,
                                                 1024);
  // 7) MLP fc2 + residual(x1) -> final x (fp32, in d_out)
  gemm_bf16<1><<<dim3(8, 32), 256, 0, stream>>>(mlph_bf, wbf_w2, b2, x1, x1,
                                                nullptr, NROW, 1024, 4096);
}

// Round 8
// 565.969 us; speedup vs baseline: 1.1175x; 1.1175x over previous
//
#include <hip/hip_runtime.h>
#include <hip/hip_bf16.h>

// B=4, S=1024, E=1024, H=16, D=64, F=4096. N=B*S=4096 tokens.
// GEMMs + attention core: bf16 MFMA (fp32 accumulate). LN/softmax: fp32.

typedef __attribute__((ext_vector_type(8))) short s16x8;
typedef __attribute__((ext_vector_type(4))) float f32x4;

static __device__ __forceinline__ unsigned short f2bf(float x) {
  unsigned int u = __builtin_bit_cast(unsigned int, x);
  u = (u + 0x7fffu + ((u >> 16) & 1u)) >> 16;  // RNE
  return (unsigned short)u;
}

#if __has_builtin(__builtin_amdgcn_global_load_lds)
#define HAVE_GLL 1
static __device__ __forceinline__ void gload16(const unsigned short* g,
                                               unsigned short* l) {
  // async global->LDS, 16 B per lane; LDS dest = wave-uniform base + lane*16
  __builtin_amdgcn_global_load_lds(
      (const __attribute__((address_space(1))) unsigned int*)g,
      (__attribute__((address_space(3))) unsigned int*)l, 16, 0, 0);
}
#endif

// ---------------------------------------------------------------------------
// fp32 -> bf16 weight conversion
// ---------------------------------------------------------------------------
__global__ __launch_bounds__(256) void cvt_bf16(const float* __restrict__ src,
                                                unsigned short* __restrict__ dst,
                                                int n) {
  const int i = (blockIdx.x * 256 + threadIdx.x) * 4;
  if (i < n) {
    const float4 v = *(const float4*)(src + i);
    ushort4 o;
    o.x = f2bf(v.x); o.y = f2bf(v.y); o.z = f2bf(v.z); o.w = f2bf(v.w);
    *(ushort4*)(dst + i) = o;
  }
}

// ---------------------------------------------------------------------------
// LayerNorm over E=1024, one block per row, bf16 output.
// ---------------------------------------------------------------------------
__global__ __launch_bounds__(256) void ln_kernel(const float* __restrict__ x,
                                                 const float* __restrict__ g,
                                                 const float* __restrict__ bvec,
                                                 unsigned short* __restrict__ y) {
  const int row = blockIdx.x;
  const int t = threadIdx.x;
  const float4 v = ((const float4*)(x + (size_t)row * 1024))[t];
  float s = v.x + v.y + v.z + v.w;
  float ss = v.x * v.x + v.y * v.y + v.z * v.z + v.w * v.w;
#pragma unroll
  for (int off = 32; off > 0; off >>= 1) {
    s += __shfl_down(s, off);
    ss += __shfl_down(ss, off);
  }
  __shared__ float sb[4], ssb[4];
  __shared__ float mrs[2];
  if ((t & 63) == 0) { sb[t >> 6] = s; ssb[t >> 6] = ss; }
  __syncthreads();
  if (t == 0) {
    float ts = sb[0] + sb[1] + sb[2] + sb[3];
    float tss = ssb[0] + ssb[1] + ssb[2] + ssb[3];
    float mean = ts * (1.0f / 1024.0f);
    float var = tss * (1.0f / 1024.0f) - mean * mean;
    mrs[0] = mean;
    mrs[1] = rsqrtf(var + 1e-5f);
  }
  __syncthreads();
  const float mean = mrs[0], rstd = mrs[1];
  const float4 gg = ((const float4*)g)[t];
  const float4 bb = ((const float4*)bvec)[t];
  ushort4 o;
  o.x = f2bf((v.x - mean) * rstd * gg.x + bb.x);
  o.y = f2bf((v.y - mean) * rstd * gg.y + bb.y);
  o.z = f2bf((v.z - mean) * rstd * gg.z + bb.z);
  o.w = f2bf((v.w - mean) * rstd * gg.w + bb.w);
  *(ushort4*)(y + (size_t)row * 1024 + t * 4) = o;
}

// ---------------------------------------------------------------------------
// C[M,N] = A[M,K] @ W[N,K]^T + bias   -- bf16 MFMA, fp32 accum.
// 128x128 tile, BK=32, 256 threads = 4 waves (2x2), 4x4 frags of 16x16x32.
// Staging: global_load_lds width-16 into linear [128][32] LDS (m97 structure).
// EPI: 1 = fp32 +res store, 2 = exact GELU -> bf16, 3 = QKV split:
//      cols<2048 -> bf16 qkv2[row][2048]; cols>=2048 -> bf16 vt (V transposed)
// ---------------------------------------------------------------------------
template <int EPI>
__global__ __launch_bounds__(256) void gemm_bf16(
    const unsigned short* __restrict__ A, const unsigned short* __restrict__ W,
    const float* __restrict__ bias, const float* __restrict__ res, void* Cv,
    void* aux, int M, int N, int K) {
  __shared__ unsigned short As[128][32];  // linear: required by global_load_lds
  __shared__ unsigned short Bs[128][32];
  const int t = threadIdx.x;
  const int m0 = blockIdx.y << 7;
  const int n0 = blockIdx.x << 7;
  const int l = t & 63;
  const int w = t >> 6;
  const int wr = (w >> 1) * 64, wc = (w & 1) * 64;
  const int lr = l & 15;
  const int kc = (l >> 4) * 8;  // k-chunk (shorts) for frag reads
  // staging map: wave w owns rows [w*16, w*16+16) and [64+w*16, ...);
  // lane l covers row base+(l>>2), 16B chunk (l&3)  (byte l*16 of wave seg)
  const int r0 = w << 4;
  const int r1 = 64 + (w << 4);
  const int lrow = l >> 2, lch = (l & 3) << 3;
  const unsigned short* Ag0 = A + (size_t)(m0 + r0 + lrow) * K + lch;
  const unsigned short* Ag1 = A + (size_t)(m0 + r1 + lrow) * K + lch;
  const unsigned short* Bg0 = W + (size_t)(n0 + r0 + lrow) * K + lch;
  const unsigned short* Bg1 = W + (size_t)(n0 + r1 + lrow) * K + lch;
#ifdef HAVE_GLL
  unsigned short* Al0 = &As[r0][0];
  unsigned short* Al1 = &As[r1][0];
  unsigned short* Bl0 = &Bs[r0][0];
  unsigned short* Bl1 = &Bs[r1][0];
#endif
  f32x4 acc[4][4] = {};
  for (int k0 = 0; k0 < K; k0 += 32) {
#ifdef HAVE_GLL
    __syncthreads();  // prior frag reads done before LDS overwrite
    gload16(Ag0 + k0, Al0);
    gload16(Ag1 + k0, Al1);
    gload16(Bg0 + k0, Bl0);
    gload16(Bg1 + k0, Bl1);
    __syncthreads();  // compiler drains vmcnt before barrier -> LDS ready
#else
    const uint4 a0 = *(const uint4*)(Ag0 + k0);
    const uint4 a1 = *(const uint4*)(Ag1 + k0);
    const uint4 b0 = *(const uint4*)(Bg0 + k0);
    const uint4 b1 = *(const uint4*)(Bg1 + k0);
    __syncthreads();
    *(uint4*)&As[r0 + lrow][lch] = a0;
    *(uint4*)&As[r1 + lrow][lch] = a1;
    *(uint4*)&Bs[r0 + lrow][lch] = b0;
    *(uint4*)&Bs[r1 + lrow][lch] = b1;
    __syncthreads();
#endif
    s16x8 af[4], bfr[4];
#pragma unroll
    for (int i = 0; i < 4; ++i) af[i] = *(const s16x8*)&As[wr + i * 16 + lr][kc];
#pragma unroll
    for (int j = 0; j < 4; ++j) bfr[j] = *(const s16x8*)&Bs[wc + j * 16 + lr][kc];
#pragma unroll
    for (int i = 0; i < 4; ++i)
#pragma unroll
      for (int j = 0; j < 4; ++j)
        acc[i][j] = __builtin_amdgcn_mfma_f32_16x16x32_bf16(af[i], bfr[j],
                                                            acc[i][j], 0, 0, 0);
  }
  // C/D layout: col = lane&15, row = (lane>>4)*4 + reg   [HW-verified]
  const int lg4 = (l >> 4) * 4;
#pragma unroll
  for (int j = 0; j < 4; ++j) {
    const int col = n0 + wc + j * 16 + lr;
    const float bj = bias[col];
#pragma unroll
    for (int i = 0; i < 4; ++i) {
      const int row0 = m0 + wr + i * 16 + lg4;
#pragma unroll
      for (int r = 0; r < 4; ++r) {
        const int row = row0 + r;
        const size_t idx = (size_t)row * N + col;
        float o = acc[i][j][r] + bj;
        if (EPI == 1) {
          ((float*)Cv)[idx] = o + res[idx];
        } else if (EPI == 2) {
          o = 0.5f * o * (1.0f + erff(o * 0.70710678118654752f));
          ((unsigned short*)Cv)[idx] = f2bf(o);
        } else {  // EPI == 3: QKV split (each n-tile is uniformly Q/K or V)
          if (col < 2048) {
            ((unsigned short*)Cv)[(size_t)row * 2048 + col] = f2bf(o);
          } else {
            // vt[b*1024 + dv][s] ; b = row>>10, s = row&1023, dv = col-2048
            const size_t vidx =
                ((size_t)((row >> 10) << 10) + (col - 2048)) * 1024 +
                (row & 1023);
            ((unsigned short*)aux)[vidx] = f2bf(o);
          }
        }
      }
    }
  }
}

// ---------------------------------------------------------------------------
// MFMA attention. Grid 256 = (b, 16-row q-tile), 512 threads = 8 waves.
// qkv2: bf16 [token][2048] (Q at 0, K at 1024). vt: bf16 [b*16+h][64 d][1024 s].
// Head-mean accumulates in REGISTERS (thread t owns row t>>5, cols (t&31)+32i
// -- same mapping as the softmax phase); attnw written once after head loop.
// LDS = 75 KB -> 2 blocks/CU.
// ---------------------------------------------------------------------------
__global__ __launch_bounds__(512, 4) void attn_mfma(
    const unsigned short* __restrict__ qkv2,
    const unsigned short* __restrict__ vt, unsigned short* __restrict__ ctx,
    float* __restrict__ attnw) {
  constexpr int PITCH = 1044;       // dwords
  __shared__ float Sc[16][PITCH];   // 66816 B
  __shared__ float Pctx[2][1024];   // 8192 B partial ctx [khalf][q*64+d]
  __shared__ float invs[16];        // total 75072 B
  const int t = threadIdx.x;
  const int w = t >> 6, l = t & 63;
  const int lr = l & 15, lg = l >> 4;
  const int b = blockIdx.x >> 6;
  const int q0 = (blockIdx.x & 63) * 16;
  const size_t qkbase = (size_t)b * 1024 * 2048;
  const unsigned short* Qrow = qkv2 + qkbase + (size_t)(q0 + lr) * 2048;
  const int j = w & 3, kh = w >> 2;
  const int smr = t >> 5, smc = t & 31;  // softmax/mean mapping
  float4 macc[8];  // head-mean accumulator: row smr, cols (smc+32i)*4..+3

#pragma unroll 1
  for (int h = 0; h < 16; ++h) {
    const int hoff = h * 64;
    // ---- Q A-frags (d-chunks 0-31, 32-63) ----
    s16x8 qf0 = *(const s16x8*)(Qrow + hoff + lg * 8);
    s16x8 qf1 = *(const s16x8*)(Qrow + hoff + 32 + lg * 8);
    // ---- QK^T: wave w handles keys [w*128, w*128+128), 8 tiles of 16 ----
    const unsigned short* Kb = qkv2 + qkbase + 1024 + hoff + lg * 8;
#pragma unroll
    for (int kt = 0; kt < 8; ++kt) {
      const int key0 = w * 128 + kt * 16;
      const unsigned short* kp = Kb + (size_t)(key0 + lr) * 2048;
      const s16x8 kf0 = *(const s16x8*)kp;
      const s16x8 kf1 = *(const s16x8*)(kp + 32);
      f32x4 s = {0.f, 0.f, 0.f, 0.f};
      s = __builtin_amdgcn_mfma_f32_16x16x32_bf16(qf0, kf0, s, 0, 0, 0);
      s = __builtin_amdgcn_mfma_f32_16x16x32_bf16(qf1, kf1, s, 0, 0, 0);
#pragma unroll
      for (int r = 0; r < 4; ++r)
        Sc[lg * 4 + r][key0 + lr] = s[r] * 0.125f;
    }
    __syncthreads();  // barrier A
    // ---- softmax (32 threads/row) + fused register head-mean accum ----
    {
      float4 f[8];
      float m = -3.4e38f;
#pragma unroll
      for (int i = 0; i < 8; ++i) {
        f[i] = *(const float4*)&Sc[smr][(smc + 32 * i) * 4];
        m = fmaxf(m, fmaxf(fmaxf(f[i].x, f[i].y), fmaxf(f[i].z, f[i].w)));
      }
#pragma unroll
      for (int off = 1; off < 32; off <<= 1) m = fmaxf(m, __shfl_xor(m, off));
      float sum = 0.f;
#pragma unroll
      for (int i = 0; i < 8; ++i) {
        f[i].x = __expf(f[i].x - m); f[i].y = __expf(f[i].y - m);
        f[i].z = __expf(f[i].z - m); f[i].w = __expf(f[i].w - m);
        sum += f[i].x + f[i].y + f[i].z + f[i].w;
        *(float4*)&Sc[smr][(smc + 32 * i) * 4] = f[i];
      }
#pragma unroll
      for (int off = 1; off < 32; off <<= 1) sum += __shfl_xor(sum, off);
      const float iv = 1.0f / sum;
      if (smc == 0) invs[smr] = iv;
      const float sc = iv * 0.0625f;  // 1/H folded in
#pragma unroll
      for (int i = 0; i < 8; ++i) {
        if (h == 0) {
          macc[i] = make_float4(f[i].x * sc, f[i].y * sc, f[i].z * sc,
                                f[i].w * sc);
        } else {
          macc[i].x += f[i].x * sc; macc[i].y += f[i].y * sc;
          macc[i].z += f[i].z * sc; macc[i].w += f[i].w * sc;
        }
      }
    }
    __syncthreads();  // barrier B (softmax Sc writes -> PV Sc reads)
    // ---- PV: partial ctx over khalf, 16 MFMA groups of 32 keys ----
    {
      const unsigned short* Vb =
          vt + ((size_t)(b * 16 + h) * 64 + j * 16 + lr) * 1024 + lg * 8;
      f32x4 acc = {0.f, 0.f, 0.f, 0.f};
#pragma unroll
      for (int g = 0; g < 16; ++g) {
        const int k0 = kh * 512 + g * 32;
        const f32x4 p0 = *(const f32x4*)&Sc[lr][k0 + lg * 8];
        const f32x4 p1 = *(const f32x4*)&Sc[lr][k0 + lg * 8 + 4];
        s16x8 pa;
#pragma unroll
        for (int i = 0; i < 4; ++i) {
          pa[i] = (short)f2bf(p0[i]);
          pa[4 + i] = (short)f2bf(p1[i]);
        }
        const s16x8 vb = *(const s16x8*)(Vb + k0);
        acc = __builtin_amdgcn_mfma_f32_16x16x32_bf16(pa, vb, acc, 0, 0, 0);
      }
#pragma unroll
      for (int r = 0; r < 4; ++r)
        Pctx[kh][(lg * 4 + r) * 64 + j * 16 + lr] = acc[r];
    }
    __syncthreads();  // barrier C
    // ---- 2-way reduce + normalized bf16 ctx store ----
    for (int e = t; e < 1024; e += 512) {
      const int q = e >> 6, d = e & 63;
      const float v = (Pctx[0][e] + Pctx[1][e]) * invs[q];
      ctx[(size_t)(b * 1024 + q0 + q) * 1024 + hoff + d] = f2bf(v);
    }
    // head-boundary: next head's Sc writes follow this head's pre-B Sc reads
    // (softmax) and pre-C reads (PV); invs/Pctx protected by barriers A/B.
  }
  // ---- single attnw write from registers ----
  {
    float4* dst = (float4*)(attnw + (size_t)(b * 1024 + q0 + smr) * 1024);
#pragma unroll
    for (int i = 0; i < 8; ++i) dst[smc + 32 * i] = macc[i];
  }
}

// ---------------------------------------------------------------------------
extern "C" void kernel_launch(void* const* d_in, const int* in_sizes, int n_in,
                              void* d_out, int out_size, void* d_ws,
                              size_t ws_size, hipStream_t stream) {
  const float* query = (const float*)d_in[0];
  const float* ln1_g = (const float*)d_in[1];
  const float* ln1_b = (const float*)d_in[2];
  const float* in_w = (const float*)d_in[3];
  const float* in_b = (const float*)d_in[4];
  const float* out_w = (const float*)d_in[5];
  const float* out_b = (const float*)d_in[6];
  const float* ln2_g = (const float*)d_in[7];
  const float* ln2_b = (const float*)d_in[8];
  const float* w1 = (const float*)d_in[9];
  const float* b1 = (const float*)d_in[10];
  const float* w2 = (const float*)d_in[11];
  const float* b2 = (const float*)d_in[12];
  float* out = (float*)d_out;

  char* wsb = (char*)d_ws;
  const size_t MB = 1u << 20;
  unsigned short* wbf_in = (unsigned short*)(wsb);             // 6 MB
  unsigned short* wbf_out = (unsigned short*)(wsb + 6 * MB);   // 2 MB
  unsigned short* wbf_w1 = (unsigned short*)(wsb + 8 * MB);    // 8 MB
  unsigned short* wbf_w2 = (unsigned short*)(wsb + 16 * MB);   // 8 MB
  unsigned short* nq_bf = (unsigned short*)(wsb + 24 * MB);    // 8 MB
  unsigned short* qkv2 = (unsigned short*)(wsb + 32 * MB);     // 16 MB (Q,K)
  unsigned short* vt = (unsigned short*)(wsb + 48 * MB);       // 8 MB (V^T)
  unsigned short* ctx_bf = (unsigned short*)(wsb + 56 * MB);   // 8 MB
  unsigned short* mlph_bf = (unsigned short*)(wsb + 32 * MB);  // 32 MB (reuse)

  float* x1 = out;                                   // [B,S,E]
  float* attnw = out + (size_t)4 * 1024 * 1024;      // [B,S,S]

  constexpr int NROW = 4096;

  // 0) weights -> bf16
  cvt_bf16<<<3072, 256, 0, stream>>>(in_w, wbf_in, 3 * 1024 * 1024);
  cvt_bf16<<<1024, 256, 0, stream>>>(out_w, wbf_out, 1024 * 1024);
  cvt_bf16<<<4096, 256, 0, stream>>>(w1, wbf_w1, 4 * 1024 * 1024);
  cvt_bf16<<<4096, 256, 0, stream>>>(w2, wbf_w2, 4 * 1024 * 1024);
  // 1) LN1 -> bf16
  ln_kernel<<<NROW, 256, 0, stream>>>(query, ln1_g, ln1_b, nq_bf);
  // 2) QKV projection -> bf16 Q,K packed + V transposed
  gemm_bf16<3><<<dim3(24, 32), 256, 0, stream>>>(nq_bf, wbf_in, in_b, nullptr,
                                                 qkv2, vt, NROW, 3072, 1024);
  // 3) MFMA attention (bf16 ctx + fp32 head-mean attn weights)
  attn_mfma<<<256, 512, 0, stream>>>(qkv2, vt, ctx_bf, attnw);
  // 4) out_proj + residual(query) -> x1 (fp32, in d_out)
  gemm_bf16<1><<<dim3(8, 32), 256, 0, stream>>>(ctx_bf, wbf_out, out_b, query,
                                                x1, nullptr, NROW, 1024, 1024);
  // 5) LN2 -> bf16
  ln_kernel<<<NROW, 256, 0, stream>>>(x1, ln2_g, ln2_b, nq_bf);
  // 6) MLP fc1 + exact GELU -> bf16
  gemm_bf16<2><<<dim3(32, 32), 256, 0, stream>>>(nq_bf, wbf_w1, b1, nullptr,
                                                 mlph_bf, nullptr, NROW, 4096,
                                                 1024);
  // 7) MLP fc2 + residual(x1) -> final x (fp32, in d_out)
  gemm_bf16<1><<<dim3(8, 32), 256, 0, stream>>>(mlph_bf, wbf_w2, b2, x1, x1,
                                                nullptr, NROW, 1024, 4096);
}